// Round 4
// baseline (469.982 us; speedup 1.0000x reference)
//
#include <hip/hip_runtime.h>

// Guided filter, R=1, EPS=1e-6, (8,3,1024,1024) fp32 — 2-load streaming version.
//
// One wave = 248 output cols (lanes 1..62 x float4), TH=16 output rows.
// Per step: 2 aligned dwordx4 loads (x,y row prefetch) -> vertical 3-sums on own
// 4 cols -> ONE shuffle layer (16 __shfl) fetches the 4 halo columns of the
// vertical sums from neighbor lanes -> A,b on 6 cols in-lane -> horizontal 3-sum
// of A,b in-lane -> rolling 3-row A,b history -> emit.
// Replication pad: clamped row indices (history-dup at top/bottom strips);
// horizontal replication via in-lane overrides at the image edge lanes
// (vsum(-2)=vsum(-1)=vsum(0); A(-1):=A(0); mirrored on the right).

typedef float f4 __attribute__((ext_vector_type(4)));

#define TH 16    // output rows per wave-strip
#define OW 248   // output cols per wave (lanes 1..62)

__global__ __launch_bounds__(256, 6) void gf_kernel(
    const float* __restrict__ xg, const float* __restrict__ yg,
    float* __restrict__ outg, int H, int W) {
  const int lane = threadIdx.x;  // block = (64,4)
  const int img = blockIdx.z;
  const size_t ibase = (size_t)img * H * W;
  const float* __restrict__ xi = xg + ibase;
  const float* __restrict__ yi = yg + ibase;
  float* __restrict__ oi = outg + ibase;

  int tx0 = blockIdx.x * OW;
  const int skipb = tx0;             // dedupe overlap cols of the clamped block
  if (tx0 > W - OW) tx0 = W - OW;
  const int ty0 = (blockIdx.y * 4 + threadIdx.y) * TH;

  const int c0 = tx0 - 4 + 4 * lane;        // this lane's 4 cols: c0..c0+3
  const int ccl = min(max(c0, 0), W - 4);   // clamped load col (16B aligned)
  const bool wok = (lane >= 1) && (lane <= 62) && (c0 >= skipb);
  const bool fixl = (c0 == 0);              // lane owns image left edge
  const bool fixr = (c0 == W - 4);          // lane owns image right edge
  const float inv9 = 1.0f / 9.0f;

  f4 x0, x1, x2, y0, y1, y2, xp, yp;        // rolling rows + prefetch
  f4 hA1, hA2, hA3, hB1, hB2, hB3;          // 3-row A,b history (b in x9 domain)
  int nextr;

  auto ldrow = [&](int rr, f4& xv, f4& yv) {
    const float* xr = xi + (size_t)rr * W;
    const float* yr = yi + (size_t)rr * W;
    xv = *(const f4*)(xr + ccl);
    yv = *(const f4*)(yr + ccl);
  };

  auto emit_row = [&](int ly, f4 xv) {
    f4 SA = hA1 + hA2 + hA3;
    f4 SB = hB1 + hB2 + hB3;   // = 9 * sum(b)
    f4 st;
#pragma unroll
    for (int j = 0; j < 4; ++j) {
      float res = (SA[j] * xv[j] + SB[j] * inv9) * inv9;
      float t = truncf(res);
      st[j] = fminf(fmaxf(t, 0.0f), 255.0f);
    }
    if (wok) {
      int gr = ty0 + ly - 2;
      __builtin_nontemporal_store(st, (f4*)(oi + (size_t)gr * W + c0));
    }
  };

  auto dup_hist = [&]() {  // push duplicate of newest A,b row (replication)
    hA1 = hA2; hA2 = hA3;
    hB1 = hB2; hB2 = hB3;
  };

  auto step_adv = [&](int ly, bool doemit, bool dopf) {
    x0 = x1; x1 = x2; x2 = xp;
    y0 = y1; y1 = y2; y2 = yp;
    if (dopf) {
      ldrow(nextr, xp, yp);
      nextr = min(nextr + 1, H - 1);
    }
    // vertical 3-sums on own 4 cols
    f4 v[4];
    v[0] = x0 + x1 + x2;                      // vx
    v[1] = y0 + y1 + y2;                      // vy
    v[2] = x0 * y0 + x1 * y1 + x2 * y2;       // vxy
    v[3] = x0 * x0 + x1 * x1 + x2 * x2;       // vxx
    // ONE shuffle layer: halo cols c0-2,c0-1,c0+4,c0+5 of each vertical sum
    float e[4][4];
#pragma unroll
    for (int q = 0; q < 4; ++q) {
      e[q][0] = __shfl_up(v[q][2], 1);        // col c0-2
      e[q][1] = __shfl_up(v[q][3], 1);        // col c0-1
      e[q][2] = __shfl_down(v[q][0], 1);      // col c0+4
      e[q][3] = __shfl_down(v[q][1], 1);      // col c0+5
    }
    if (fixl) {  // cols -2,-1 replicate col 0
#pragma unroll
      for (int q = 0; q < 4; ++q) { e[q][0] = v[q][0]; e[q][1] = v[q][0]; }
    }
    if (fixr) {  // cols W,W+1 replicate col W-1
#pragma unroll
      for (int q = 0; q < 4; ++q) { e[q][2] = v[q][3]; e[q][3] = v[q][3]; }
    }
    // 8-col views (index i = image col c0-2+i)
    float wx[8]  = {e[0][0], e[0][1], v[0][0], v[0][1], v[0][2], v[0][3], e[0][2], e[0][3]};
    float wy[8]  = {e[1][0], e[1][1], v[1][0], v[1][1], v[1][2], v[1][3], e[1][2], e[1][3]};
    float wxy[8] = {e[2][0], e[2][1], v[2][0], v[2][1], v[2][2], v[2][3], e[2][2], e[2][3]};
    float wxx[8] = {e[3][0], e[3][1], v[3][0], v[3][1], v[3][2], v[3][3], e[3][2], e[3][3]};
    // A, b(x9) for 6 cols (col c0-1+j), all in-lane
    float A[6], B[6];
#pragma unroll
    for (int j = 0; j < 6; ++j) {
      float Sx  = wx[j] + wx[j + 1] + wx[j + 2];
      float Sy  = wy[j] + wy[j + 1] + wy[j + 2];
      float Sxy = wxy[j] + wxy[j + 1] + wxy[j + 2];
      float Sxx = wxx[j] + wxx[j + 1] + wxx[j + 2];
      float num = 9.0f * Sxy - Sx * Sy;
      float den = 9.0f * Sxx - Sx * Sx + 8.1e-05f;  // >0 (Cauchy-Schwarz)
      float rd;
      asm("v_rcp_f32 %0, %1" : "=v"(rd) : "v"(den));
      float a = num * rd;
      A[j] = a;
      B[j] = Sy - a * Sx;   // 9*b
    }
    // image-edge replication of A,b (in-lane)
    if (fixl) { A[0] = A[1]; B[0] = B[1]; }
    if (fixr) { A[5] = A[4]; B[5] = B[4]; }
    // horizontal 3-sum for the 4 output cols
    f4 hAn, hBn;
#pragma unroll
    for (int j = 0; j < 4; ++j) {
      hAn[j] = A[j] + A[j + 1] + A[j + 2];
      hBn[j] = B[j] + B[j + 1] + B[j + 2];
    }
    hA1 = hA2; hA2 = hA3; hA3 = hAn;
    hB1 = hB2; hB2 = hB3; hB3 = hBn;
    if (doemit) emit_row(ly, x0);
  };

  // ---- prologue: prime rolling window ----
  {
    int cy0 = max(ty0 - 1, 0);  // center row of step 0
    int ra = max(cy0 - 1, 0);
    ldrow(ra, x1, y1);
    ldrow(cy0, x2, y2);
    nextr = min(cy0 + 1, H - 1);
    ldrow(nextr, xp, yp);
    nextr = min(nextr + 1, H - 1);
  }
  hA1 = hA2 = hA3 = (f4)(0.0f);
  hB1 = hB2 = hB3 = (f4)(0.0f);

  // ly=0: computes A-row ty0-1 (top strips: replicated row via clamped window)
  step_adv(0, false, true);
  // ly=1: top strips duplicate (center row stuck at 0); others advance
  if (ty0 == 0) dup_hist();
  else step_adv(1, false, true);
  // ly=2..TH: regular advancing+emitting steps
#pragma unroll 4
  for (int ly = 2; ly <= TH; ++ly) step_adv(ly, true, true);
  // ly=TH+1: bottom strip duplicates last A-row; others advance normally
  if (ty0 == H - TH) {
    dup_hist();
    emit_row(TH + 1, x1);  // output row H-1: x from window center
  } else {
    step_adv(TH + 1, true, false);
  }
}

extern "C" void kernel_launch(void* const* d_in, const int* in_sizes, int n_in,
                              void* d_out, int out_size, void* d_ws, size_t ws_size,
                              hipStream_t stream) {
  const float* x = (const float*)d_in[0];
  const float* y = (const float*)d_in[1];
  float* out = (float*)d_out;
  const int H = 1024, W = 1024;
  const int imgs = in_sizes[0] / (H * W);  // 8*3 = 24
  dim3 block(64, 4, 1);
  dim3 grid((W + OW - 1) / OW, H / (TH * 4), imgs);
  gf_kernel<<<grid, block, 0, stream>>>(x, y, out, H, W);
}

// Round 5
// 260.314 us; speedup vs baseline: 1.8054x; 1.8054x over previous
//
#include <hip/hip_runtime.h>

// Guided filter, R=1, EPS=1e-6, (8,3,1024,1024) fp32 — 2-load streaming version.
//
// One wave = 248 output cols (lanes 1..62 x float4), TH=16 output rows.
// Per step: 2 aligned dwordx4 loads (x,y row prefetch) -> vertical 3-sums on own
// 4 cols -> ONE shuffle layer (16 __shfl) fetches the 4 halo columns of the
// vertical sums from neighbor lanes -> A,b on 6 cols in-lane -> horizontal 3-sum
// of A,b in-lane -> rolling 3-row A,b history -> emit.
// Replication pad: clamped row indices (history-dup at top/bottom strips);
// horizontal replication via in-lane overrides at the image edge lanes
// (vsum(-2)=vsum(-1)=vsum(0); A(-1):=A(0); mirrored on the right).
//
// NOTE: no min-waves launch_bounds — R4's (256,6) capped VGPR at 40 and spilled
// the rolling window to scratch (FETCH +356MB, WRITE +312MB, 3x slowdown).

typedef float f4 __attribute__((ext_vector_type(4)));

#define TH 16    // output rows per wave-strip
#define OW 248   // output cols per wave (lanes 1..62)

__global__ __launch_bounds__(256) void gf_kernel(
    const float* __restrict__ xg, const float* __restrict__ yg,
    float* __restrict__ outg, int H, int W) {
  const int lane = threadIdx.x;  // block = (64,4)
  const int img = blockIdx.z;
  const size_t ibase = (size_t)img * H * W;
  const float* __restrict__ xi = xg + ibase;
  const float* __restrict__ yi = yg + ibase;
  float* __restrict__ oi = outg + ibase;

  int tx0 = blockIdx.x * OW;
  const int skipb = tx0;             // dedupe overlap cols of the clamped block
  if (tx0 > W - OW) tx0 = W - OW;
  const int ty0 = (blockIdx.y * 4 + threadIdx.y) * TH;

  const int c0 = tx0 - 4 + 4 * lane;        // this lane's 4 cols: c0..c0+3
  const int ccl = min(max(c0, 0), W - 4);   // clamped load col (16B aligned)
  const bool wok = (lane >= 1) && (lane <= 62) && (c0 >= skipb);
  const bool fixl = (c0 == 0);              // lane owns image left edge
  const bool fixr = (c0 == W - 4);          // lane owns image right edge
  const float inv9 = 1.0f / 9.0f;

  f4 x0, x1, x2, y0, y1, y2, xp, yp;        // rolling rows + prefetch
  f4 hA1, hA2, hA3, hB1, hB2, hB3;          // 3-row A,b history (b in x9 domain)
  int nextr;

  auto ldrow = [&](int rr, f4& xv, f4& yv) {
    const float* xr = xi + (size_t)rr * W;
    const float* yr = yi + (size_t)rr * W;
    xv = *(const f4*)(xr + ccl);
    yv = *(const f4*)(yr + ccl);
  };

  auto emit_row = [&](int ly, f4 xv) {
    f4 SA = hA1 + hA2 + hA3;
    f4 SB = hB1 + hB2 + hB3;   // = 9 * sum(b)
    f4 st;
#pragma unroll
    for (int j = 0; j < 4; ++j) {
      float res = (SA[j] * xv[j] + SB[j] * inv9) * inv9;
      float t = truncf(res);
      st[j] = fminf(fmaxf(t, 0.0f), 255.0f);
    }
    if (wok) {
      int gr = ty0 + ly - 2;
      __builtin_nontemporal_store(st, (f4*)(oi + (size_t)gr * W + c0));
    }
  };

  auto dup_hist = [&]() {  // push duplicate of newest A,b row (replication)
    hA1 = hA2; hA2 = hA3;
    hB1 = hB2; hB2 = hB3;
  };

  auto step_adv = [&](int ly, bool doemit, bool dopf) {
    x0 = x1; x1 = x2; x2 = xp;
    y0 = y1; y1 = y2; y2 = yp;
    if (dopf) {
      ldrow(nextr, xp, yp);
      nextr = min(nextr + 1, H - 1);
    }
    // vertical 3-sums on own 4 cols
    f4 v[4];
    v[0] = x0 + x1 + x2;                      // vx
    v[1] = y0 + y1 + y2;                      // vy
    v[2] = x0 * y0 + x1 * y1 + x2 * y2;       // vxy
    v[3] = x0 * x0 + x1 * x1 + x2 * x2;       // vxx
    // ONE shuffle layer: halo cols c0-2,c0-1,c0+4,c0+5 of each vertical sum
    float e[4][4];
#pragma unroll
    for (int q = 0; q < 4; ++q) {
      e[q][0] = __shfl_up(v[q][2], 1);        // col c0-2
      e[q][1] = __shfl_up(v[q][3], 1);        // col c0-1
      e[q][2] = __shfl_down(v[q][0], 1);      // col c0+4
      e[q][3] = __shfl_down(v[q][1], 1);      // col c0+5
    }
    if (fixl) {  // cols -2,-1 replicate col 0
#pragma unroll
      for (int q = 0; q < 4; ++q) { e[q][0] = v[q][0]; e[q][1] = v[q][0]; }
    }
    if (fixr) {  // cols W,W+1 replicate col W-1
#pragma unroll
      for (int q = 0; q < 4; ++q) { e[q][2] = v[q][3]; e[q][3] = v[q][3]; }
    }
    // 8-col views (index i = image col c0-2+i)
    float wx[8]  = {e[0][0], e[0][1], v[0][0], v[0][1], v[0][2], v[0][3], e[0][2], e[0][3]};
    float wy[8]  = {e[1][0], e[1][1], v[1][0], v[1][1], v[1][2], v[1][3], e[1][2], e[1][3]};
    float wxy[8] = {e[2][0], e[2][1], v[2][0], v[2][1], v[2][2], v[2][3], e[2][2], e[2][3]};
    float wxx[8] = {e[3][0], e[3][1], v[3][0], v[3][1], v[3][2], v[3][3], e[3][2], e[3][3]};
    // A, b(x9) for 6 cols (col c0-1+j), all in-lane
    float A[6], B[6];
#pragma unroll
    for (int j = 0; j < 6; ++j) {
      float Sx  = wx[j] + wx[j + 1] + wx[j + 2];
      float Sy  = wy[j] + wy[j + 1] + wy[j + 2];
      float Sxy = wxy[j] + wxy[j + 1] + wxy[j + 2];
      float Sxx = wxx[j] + wxx[j + 1] + wxx[j + 2];
      float num = 9.0f * Sxy - Sx * Sy;
      float den = 9.0f * Sxx - Sx * Sx + 8.1e-05f;  // >0 (Cauchy-Schwarz)
      float rd;
      asm("v_rcp_f32 %0, %1" : "=v"(rd) : "v"(den));
      float a = num * rd;
      A[j] = a;
      B[j] = Sy - a * Sx;   // 9*b
    }
    // image-edge replication of A,b (in-lane)
    if (fixl) { A[0] = A[1]; B[0] = B[1]; }
    if (fixr) { A[5] = A[4]; B[5] = B[4]; }
    // horizontal 3-sum for the 4 output cols
    f4 hAn, hBn;
#pragma unroll
    for (int j = 0; j < 4; ++j) {
      hAn[j] = A[j] + A[j + 1] + A[j + 2];
      hBn[j] = B[j] + B[j + 1] + B[j + 2];
    }
    hA1 = hA2; hA2 = hA3; hA3 = hAn;
    hB1 = hB2; hB2 = hB3; hB3 = hBn;
    if (doemit) emit_row(ly, x0);
  };

  // ---- prologue: prime rolling window ----
  {
    int cy0 = max(ty0 - 1, 0);  // center row of step 0
    int ra = max(cy0 - 1, 0);
    ldrow(ra, x1, y1);
    ldrow(cy0, x2, y2);
    nextr = min(cy0 + 1, H - 1);
    ldrow(nextr, xp, yp);
    nextr = min(nextr + 1, H - 1);
  }
  hA1 = hA2 = hA3 = (f4)(0.0f);
  hB1 = hB2 = hB3 = (f4)(0.0f);

  // ly=0: computes A-row ty0-1 (top strips: replicated row via clamped window)
  step_adv(0, false, true);
  // ly=1: top strips duplicate (center row stuck at 0); others advance
  if (ty0 == 0) dup_hist();
  else step_adv(1, false, true);
  // ly=2..TH: regular advancing+emitting steps
#pragma unroll 4
  for (int ly = 2; ly <= TH; ++ly) step_adv(ly, true, true);
  // ly=TH+1: bottom strip duplicates last A-row; others advance normally
  if (ty0 == H - TH) {
    dup_hist();
    emit_row(TH + 1, x1);  // output row H-1: x from window center
  } else {
    step_adv(TH + 1, true, false);
  }
}

extern "C" void kernel_launch(void* const* d_in, const int* in_sizes, int n_in,
                              void* d_out, int out_size, void* d_ws, size_t ws_size,
                              hipStream_t stream) {
  const float* x = (const float*)d_in[0];
  const float* y = (const float*)d_in[1];
  float* out = (float*)d_out;
  const int H = 1024, W = 1024;
  const int imgs = in_sizes[0] / (H * W);  // 8*3 = 24
  dim3 block(64, 4, 1);
  dim3 grid((W + OW - 1) / OW, H / (TH * 4), imgs);
  gf_kernel<<<grid, block, 0, stream>>>(x, y, out, H, W);
}

// Round 8
// 253.887 us; speedup vs baseline: 1.8511x; 1.0253x over previous
//
#include <hip/hip_runtime.h>

// Guided filter, R=1, EPS=1e-6, (8,3,1024,1024) fp32 — 2-load streaming version.
//
// One wave = 248 output cols (lanes 1..62 x float4), TH=8 output rows.
// Per step: 2 aligned dwordx4 loads (x,y row prefetch) -> vertical 3-sums on own
// 4 cols -> ONE shuffle layer (16 __shfl) fetches the 4 halo columns of the
// vertical sums from neighbor lanes -> A,b on 6 cols in-lane -> horizontal 3-sum
// of A,b in-lane -> rolling 3-row A,b history -> emit.
// Replication pad: clamped row indices (history-dup at top/bottom strips);
// horizontal replication via in-lane overrides at the image edge lanes.
//
// R7 diffs vs R5 (known-good): TH 16->8 (2x wave count: 15360 waves, VGPR<=64
// allows 8/SIMD residency) and FULL unroll of the step loop (R5's unroll-4 vs
// rotation-period-3/4 mismatch emitted ~50 v_mov/step of register shifting;
// full unroll lets the compiler rename all shifts away).
// NOTE: no min-waves launch_bounds — R4's (256,6) capped VGPR at 40 and spilled.

typedef float f4 __attribute__((ext_vector_type(4)));

#define TH 8     // output rows per wave-strip
#define OW 248   // output cols per wave (lanes 1..62)

__global__ __launch_bounds__(256) void gf_kernel(
    const float* __restrict__ xg, const float* __restrict__ yg,
    float* __restrict__ outg, int H, int W) {
  const int lane = threadIdx.x;  // block = (64,4)
  const int img = blockIdx.z;
  const size_t ibase = (size_t)img * H * W;
  const float* __restrict__ xi = xg + ibase;
  const float* __restrict__ yi = yg + ibase;
  float* __restrict__ oi = outg + ibase;

  int tx0 = blockIdx.x * OW;
  const int skipb = tx0;             // dedupe overlap cols of the clamped block
  if (tx0 > W - OW) tx0 = W - OW;
  const int ty0 = (blockIdx.y * 4 + threadIdx.y) * TH;

  const int c0 = tx0 - 4 + 4 * lane;        // this lane's 4 cols: c0..c0+3
  const int ccl = min(max(c0, 0), W - 4);   // clamped load col (16B aligned)
  const bool wok = (lane >= 1) && (lane <= 62) && (c0 >= skipb);
  const bool fixl = (c0 == 0);              // lane owns image left edge
  const bool fixr = (c0 == W - 4);          // lane owns image right edge
  const float inv9 = 1.0f / 9.0f;

  f4 x0, x1, x2, y0, y1, y2, xp, yp;        // rolling rows + prefetch
  f4 hA1, hA2, hA3, hB1, hB2, hB3;          // 3-row A,b history (b in x9 domain)
  int nextr;

  auto ldrow = [&](int rr, f4& xv, f4& yv) {
    const float* xr = xi + (size_t)rr * W;
    const float* yr = yi + (size_t)rr * W;
    xv = *(const f4*)(xr + ccl);
    yv = *(const f4*)(yr + ccl);
  };

  auto emit_row = [&](int ly, f4 xv) {
    f4 SA = hA1 + hA2 + hA3;
    f4 SB = hB1 + hB2 + hB3;   // = 9 * sum(b)
    f4 st;
#pragma unroll
    for (int j = 0; j < 4; ++j) {
      float res = (SA[j] * xv[j] + SB[j] * inv9) * inv9;
      float t = truncf(res);
      st[j] = fminf(fmaxf(t, 0.0f), 255.0f);
    }
    if (wok) {
      int gr = ty0 + ly - 2;
      __builtin_nontemporal_store(st, (f4*)(oi + (size_t)gr * W + c0));
    }
  };

  auto dup_hist = [&]() {  // push duplicate of newest A,b row (replication)
    hA1 = hA2; hA2 = hA3;
    hB1 = hB2; hB2 = hB3;
  };

  auto step_adv = [&](int ly, bool doemit, bool dopf) {
    x0 = x1; x1 = x2; x2 = xp;
    y0 = y1; y1 = y2; y2 = yp;
    if (dopf) {
      ldrow(nextr, xp, yp);
      nextr = min(nextr + 1, H - 1);
    }
    // vertical 3-sums on own 4 cols
    f4 v[4];
    v[0] = x0 + x1 + x2;                      // vx
    v[1] = y0 + y1 + y2;                      // vy
    v[2] = x0 * y0 + x1 * y1 + x2 * y2;       // vxy
    v[3] = x0 * x0 + x1 * x1 + x2 * x2;       // vxx
    // ONE shuffle layer: halo cols c0-2,c0-1,c0+4,c0+5 of each vertical sum
    float e[4][4];
#pragma unroll
    for (int q = 0; q < 4; ++q) {
      e[q][0] = __shfl_up(v[q][2], 1);        // col c0-2
      e[q][1] = __shfl_up(v[q][3], 1);        // col c0-1
      e[q][2] = __shfl_down(v[q][0], 1);      // col c0+4
      e[q][3] = __shfl_down(v[q][1], 1);      // col c0+5
    }
    if (fixl) {  // cols -2,-1 replicate col 0
#pragma unroll
      for (int q = 0; q < 4; ++q) { e[q][0] = v[q][0]; e[q][1] = v[q][0]; }
    }
    if (fixr) {  // cols W,W+1 replicate col W-1
#pragma unroll
      for (int q = 0; q < 4; ++q) { e[q][2] = v[q][3]; e[q][3] = v[q][3]; }
    }
    // 8-col views (index i = image col c0-2+i)
    float wx[8]  = {e[0][0], e[0][1], v[0][0], v[0][1], v[0][2], v[0][3], e[0][2], e[0][3]};
    float wy[8]  = {e[1][0], e[1][1], v[1][0], v[1][1], v[1][2], v[1][3], e[1][2], e[1][3]};
    float wxy[8] = {e[2][0], e[2][1], v[2][0], v[2][1], v[2][2], v[2][3], e[2][2], e[2][3]};
    float wxx[8] = {e[3][0], e[3][1], v[3][0], v[3][1], v[3][2], v[3][3], e[3][2], e[3][3]};
    // A, b(x9) for 6 cols (col c0-1+j), all in-lane
    float A[6], B[6];
#pragma unroll
    for (int j = 0; j < 6; ++j) {
      float Sx  = wx[j] + wx[j + 1] + wx[j + 2];
      float Sy  = wy[j] + wy[j + 1] + wy[j + 2];
      float Sxy = wxy[j] + wxy[j + 1] + wxy[j + 2];
      float Sxx = wxx[j] + wxx[j + 1] + wxx[j + 2];
      float num = 9.0f * Sxy - Sx * Sy;
      float den = 9.0f * Sxx - Sx * Sx + 8.1e-05f;  // >0 (Cauchy-Schwarz)
      float rd;
      asm("v_rcp_f32 %0, %1" : "=v"(rd) : "v"(den));
      float a = num * rd;
      A[j] = a;
      B[j] = Sy - a * Sx;   // 9*b
    }
    // image-edge replication of A,b (in-lane)
    if (fixl) { A[0] = A[1]; B[0] = B[1]; }
    if (fixr) { A[5] = A[4]; B[5] = B[4]; }
    // horizontal 3-sum for the 4 output cols
    f4 hAn, hBn;
#pragma unroll
    for (int j = 0; j < 4; ++j) {
      hAn[j] = A[j] + A[j + 1] + A[j + 2];
      hBn[j] = B[j] + B[j + 1] + B[j + 2];
    }
    hA1 = hA2; hA2 = hA3; hA3 = hAn;
    hB1 = hB2; hB2 = hB3; hB3 = hBn;
    if (doemit) emit_row(ly, x0);
  };

  // ---- prologue: prime rolling window ----
  {
    int cy0 = max(ty0 - 1, 0);  // center row of step 0
    int ra = max(cy0 - 1, 0);
    ldrow(ra, x1, y1);
    ldrow(cy0, x2, y2);
    nextr = min(cy0 + 1, H - 1);
    ldrow(nextr, xp, yp);
    nextr = min(nextr + 1, H - 1);
  }
  hA1 = hA2 = hA3 = (f4)(0.0f);
  hB1 = hB2 = hB3 = (f4)(0.0f);

  // ly=0: computes A-row ty0-1 (top strips: replicated row via clamped window)
  step_adv(0, false, true);
  // ly=1: top strips duplicate (center row stuck at 0); others advance
  if (ty0 == 0) dup_hist();
  else step_adv(1, false, true);
  // ly=2..TH: regular advancing+emitting steps — FULL unroll (renaming-clean)
#pragma unroll
  for (int ly = 2; ly <= TH; ++ly) step_adv(ly, true, true);
  // ly=TH+1: bottom strip duplicates last A-row; others advance normally
  if (ty0 == H - TH) {
    dup_hist();
    emit_row(TH + 1, x1);  // output row H-1: x from window center
  } else {
    step_adv(TH + 1, true, false);
  }
}

extern "C" void kernel_launch(void* const* d_in, const int* in_sizes, int n_in,
                              void* d_out, int out_size, void* d_ws, size_t ws_size,
                              hipStream_t stream) {
  const float* x = (const float*)d_in[0];
  const float* y = (const float*)d_in[1];
  float* out = (float*)d_out;
  const int H = 1024, W = 1024;
  const int imgs = in_sizes[0] / (H * W);  // 8*3 = 24
  dim3 block(64, 4, 1);
  dim3 grid((W + OW - 1) / OW, H / (TH * 4), imgs);
  gf_kernel<<<grid, block, 0, stream>>>(x, y, out, H, W);
}